// Round 1
// baseline (504.736 us; speedup 1.0000x reference)
//
#include <hip/hip_runtime.h>

#define S_LEN 2048
#define E_DIM 1024
#define NH 16
#define HD 64
// (1/sqrt(64)) * log2(e): fold softmax scale into log2 domain
#define SCALE_L2E 0.18033688011112042f

typedef __bf16 bf16;
typedef __attribute__((ext_vector_type(4))) bf16 bf16x4;
typedef __attribute__((ext_vector_type(8))) bf16 bf16x8;
typedef __attribute__((ext_vector_type(4))) float f32x4;
typedef unsigned long long u64;

#define MFMA(a, b, c) __builtin_amdgcn_mfma_f32_16x16x32_bf16((a), (b), (c), 0, 0, 0)

__device__ __forceinline__ bf16x8 cvt8(f32x4 a, f32x4 b) {
  bf16x8 r;
  r[0] = (bf16)a[0]; r[1] = (bf16)a[1]; r[2] = (bf16)a[2]; r[3] = (bf16)a[3];
  r[4] = (bf16)b[0]; r[5] = (bf16)b[1]; r[6] = (bf16)b[2]; r[7] = (bf16)b[3];
  return r;
}

// A/B fragment for 16x16x32: lane holds outer index = lane&15,
// k = 4*(lane>>4) + (i&3) + 16*(i>>2)  -> two contiguous 4-element chunks at p and p+16
__device__ __forceinline__ bf16x8 load_frag(const bf16* p) {
  bf16x4 lo = *(const bf16x4*)p;
  bf16x4 hi = *(const bf16x4*)(p + 16);
  return __builtin_shufflevector(lo, hi, 0, 1, 2, 3, 4, 5, 6, 7);
}

__device__ __forceinline__ bf16x8 load_cvt_frag(const float* p) {
  f32x4 a = *(const f32x4*)p;
  f32x4 b = *(const f32x4*)(p + 16);
  return cvt8(a, b);
}

// ---------------- mask bit-pack: (S,S) int32 -> S*S/64 uint64 ----------------
__global__ __launch_bounds__(256) void pack_mask_k(const int* __restrict__ mask,
                                                   u64* __restrict__ bits) {
  const int w = blockIdx.x * 4 + (threadIdx.x >> 6);
  const int lane = threadIdx.x & 63;
  const int v = mask[(size_t)w * 64 + lane];
  const u64 b = __ballot(v != 0);
  if (lane == 0) bits[w] = b;
}

// ---------------- K/V projection: Kp (b,h,s,d) row-major; VpT (b,h,d,s) ----------------
__global__ __launch_bounds__(256) void kvproj_k(
    const float* __restrict__ Kin, const float* __restrict__ Vin,
    const float* __restrict__ Wk, const float* __restrict__ bk,
    const float* __restrict__ Wv, const float* __restrict__ bv,
    bf16* __restrict__ Kp, bf16* __restrict__ VpT) {
  const int blk = blockIdx.x;
  const int sblk = blk & 31;            // S/64 = 32
  const int h = (blk >> 5) & (NH - 1);
  const int b = blk >> 9;
  const int lane = threadIdx.x & 63;
  const int wave = threadIdx.x >> 6;
  const int g = lane >> 4;
  const int c16 = lane & 15;
  const int sbase = sblk * 64 + wave * 16;
  const int srow = sbase + c16;

  const float* xk = Kin + ((size_t)b * S_LEN + srow) * E_DIM + h * HD;
  const float* xv = Vin + ((size_t)b * S_LEN + srow) * E_DIM + h * HD;
  bf16x8 xkf[2], xvf[2];
#pragma unroll
  for (int c = 0; c < 2; ++c) {
    xkf[c] = load_cvt_frag(xk + 32 * c + 4 * g);
    xvf[c] = load_cvt_frag(xv + 32 * c + 4 * g);
  }
  const size_t bh = (size_t)b * NH + h;

  // Kp = Xk * Wk^T + bk  : A = Xk (m=s, k=d_in), B = Wk^T (lane reads Wk row 16nt+c16)
#pragma unroll
  for (int nt = 0; nt < 4; ++nt) {
    const float* wr = Wk + (16 * nt + c16) * HD + 4 * g;
    f32x4 acc = {0.f, 0.f, 0.f, 0.f};
    acc = MFMA(xkf[0], load_cvt_frag(wr), acc);
    acc = MFMA(xkf[1], load_cvt_frag(wr + 32), acc);
    const float bias = bk[16 * nt + c16];
#pragma unroll
    for (int r = 0; r < 4; ++r)
      Kp[(bh * S_LEN + sbase + 4 * g + r) * HD + 16 * nt + c16] = (bf16)(acc[r] + bias);
  }
  // VpT = Wv * Xv^T + bv : A = Wv (m=d_out), B = Xv^T (n=s)
#pragma unroll
  for (int nt = 0; nt < 4; ++nt) {
    const float* wr = Wv + (16 * nt + c16) * HD + 4 * g;
    f32x4 acc = {0.f, 0.f, 0.f, 0.f};
    acc = MFMA(load_cvt_frag(wr), xvf[0], acc);
    acc = MFMA(load_cvt_frag(wr + 32), xvf[1], acc);
#pragma unroll
    for (int r = 0; r < 4; ++r) {
      const int dout = 16 * nt + 4 * g + r;
      VpT[(bh * HD + dout) * S_LEN + srow] = (bf16)(acc[r] + bv[dout]);
    }
  }
}

// ---------------- attention: fused Q-proj + swapped-operand flash ----------------
__global__ __launch_bounds__(256) void attn_k(
    const float* __restrict__ Qin, const float* __restrict__ Wq, const float* __restrict__ bq,
    const bf16* __restrict__ Kp, const bf16* __restrict__ VpT,
    const u64* __restrict__ mbits, float* __restrict__ out) {
  const int blk = blockIdx.x;
  const int qblk = blk & 31;
  const int h = (blk >> 5) & (NH - 1);
  const int b = blk >> 9;
  const int lane = threadIdx.x & 63;
  const int wave = threadIdx.x >> 6;
  const int g = lane >> 4;
  const int c16 = lane & 15;
  const int qbase = qblk * 64 + wave * 16;
  const int qrow = qbase + c16;   // each lane owns ONE q row (swapped layout)
  const size_t bh = (size_t)b * NH + h;

  // Q projection in-register: QpT = Wq * Xq^T + bq; C-tiles ARE the QK B-frags.
  const float* xq = Qin + ((size_t)b * S_LEN + qrow) * E_DIM + h * HD;
  bf16x8 xqf[2];
#pragma unroll
  for (int c = 0; c < 2; ++c) xqf[c] = load_cvt_frag(xq + 32 * c + 4 * g);
  f32x4 qt[4];
#pragma unroll
  for (int t = 0; t < 4; ++t) {
    const float* wr = Wq + (16 * t + c16) * HD + 4 * g;
    f32x4 acc = {0.f, 0.f, 0.f, 0.f};
    acc = MFMA(load_cvt_frag(wr), xqf[0], acc);
    acc = MFMA(load_cvt_frag(wr + 32), xqf[1], acc);
#pragma unroll
    for (int r = 0; r < 4; ++r) acc[r] += bq[16 * t + 4 * g + r];
    qt[t] = acc;
  }
  bf16x8 qfrag[2];
#pragma unroll
  for (int c = 0; c < 2; ++c) qfrag[c] = cvt8(qt[2 * c], qt[2 * c + 1]);

  const bf16* kbase_p = Kp + bh * S_LEN * HD;
  const bf16* vbase_p = VpT + bh * HD * S_LEN;
  const u64* mrow = mbits + (size_t)qrow * (S_LEN / 64);

  float m = -1e30f, l = 0.f;
  f32x4 o[4] = {};

  for (int kb = 0; kb < S_LEN / 64; ++kb) {
    // S^T tiles: st[ks][r] = score(key = kb*64 + 16*ks + 4*g + r, q = qrow)
    f32x4 st[4];
#pragma unroll
    for (int ks = 0; ks < 4; ++ks) {
      const bf16* kr = kbase_p + (size_t)(kb * 64 + 16 * ks + c16) * HD + 4 * g;
      f32x4 acc = {0.f, 0.f, 0.f, 0.f};
      acc = MFMA(load_frag(kr), qfrag[0], acc);
      acc = MFMA(load_frag(kr + 32), qfrag[1], acc);
      st[ks] = acc;
    }
    const u64 mw = mrow[kb];
    float tm = -1e30f;
#pragma unroll
    for (int ks = 0; ks < 4; ++ks)
#pragma unroll
      for (int r = 0; r < 4; ++r) {
        const float x =
            ((mw >> (16 * ks + 4 * g + r)) & 1ull) ? st[ks][r] * SCALE_L2E : -1e30f;
        st[ks][r] = x;
        tm = fmaxf(tm, x);
      }
    tm = fmaxf(tm, __shfl_xor(tm, 16));
    tm = fmaxf(tm, __shfl_xor(tm, 32));
    const float mnew = fmaxf(m, tm);
    const float corr = exp2f(m - mnew);
    float psum = 0.f;
#pragma unroll
    for (int ks = 0; ks < 4; ++ks)
#pragma unroll
      for (int r = 0; r < 4; ++r) {
        const float p = exp2f(st[ks][r] - mnew);
        st[ks][r] = p;
        psum += p;
      }
    psum += __shfl_xor(psum, 16);
    psum += __shfl_xor(psum, 32);
    l = l * corr + psum;
    m = mnew;
#pragma unroll
    for (int t = 0; t < 4; ++t)
#pragma unroll
      for (int r = 0; r < 4; ++r) o[t][r] *= corr;
    // P^T C-tiles are directly the PV B-frags
    bf16x8 pfrag[2];
#pragma unroll
    for (int c = 0; c < 2; ++c) pfrag[c] = cvt8(st[2 * c], st[2 * c + 1]);
#pragma unroll
    for (int t = 0; t < 4; ++t) {
      const bf16* vr = vbase_p + (size_t)(16 * t + c16) * S_LEN + kb * 64 + 4 * g;
      o[t] = MFMA(load_frag(vr), pfrag[0], o[t]);
      o[t] = MFMA(load_frag(vr + 32), pfrag[1], o[t]);
    }
  }

  const float inv = 1.0f / l;
  float* orow = out + ((size_t)b * S_LEN + qrow) * E_DIM + h * HD;
#pragma unroll
  for (int t = 0; t < 4; ++t) {
    f32x4 v;
#pragma unroll
    for (int r = 0; r < 4; ++r) v[r] = o[t][r] * inv;
    *(f32x4*)(orow + 16 * t + 4 * g) = v;
  }
}

extern "C" void kernel_launch(void* const* d_in, const int* in_sizes, int n_in,
                              void* d_out, int out_size, void* d_ws, size_t ws_size,
                              hipStream_t stream) {
  const float* Q = (const float*)d_in[0];
  const float* K = (const float*)d_in[1];
  const float* V = (const float*)d_in[2];
  const int* mask = (const int*)d_in[3];
  const float* Wq = (const float*)d_in[4];
  const float* bq = (const float*)d_in[5];
  const float* Wk = (const float*)d_in[6];
  const float* bk = (const float*)d_in[7];
  const float* Wv = (const float*)d_in[8];
  const float* bv = (const float*)d_in[9];
  float* out = (float*)d_out;
  const int B = in_sizes[0] / (S_LEN * E_DIM);   // = 2

  char* ws = (char*)d_ws;
  const size_t proj_bytes = (size_t)B * NH * S_LEN * HD * 2;  // 8 MB each
  bf16* Kp = (bf16*)ws;
  bf16* VpT = (bf16*)(ws + proj_bytes);
  u64* mbits = (u64*)(ws + 2 * proj_bytes);      // 512 KB

  pack_mask_k<<<(S_LEN * S_LEN / 64) / 4, 256, 0, stream>>>(mask, mbits);
  kvproj_k<<<B * NH * (S_LEN / 64), 256, 0, stream>>>(K, V, Wk, bk, Wv, bv, Kp, VpT);
  attn_k<<<B * NH * (S_LEN / 64), 256, 0, stream>>>(Q, Wq, bq, Kp, VpT, mbits, out);
}

// Round 2
// 207.348 us; speedup vs baseline: 2.4342x; 2.4342x over previous
//
#include <hip/hip_runtime.h>

#define S_LEN 2048
#define E_DIM 1024
#define NH 16
#define HD 64
// (1/sqrt(64)) * log2(e): fold softmax scale into log2 domain
#define SCALE_L2E 0.18033688011112042f

typedef __bf16 bf16;
typedef __attribute__((ext_vector_type(4))) bf16 bf16x4;
typedef __attribute__((ext_vector_type(8))) bf16 bf16x8;
typedef __attribute__((ext_vector_type(4))) float f32x4;
typedef unsigned long long u64;

#define MFMA(a, b, c) __builtin_amdgcn_mfma_f32_16x16x32_bf16((a), (b), (c), 0, 0, 0)

__device__ __forceinline__ bf16x8 cvt8(f32x4 a, f32x4 b) {
  bf16x8 r;
  r[0] = (bf16)a[0]; r[1] = (bf16)a[1]; r[2] = (bf16)a[2]; r[3] = (bf16)a[3];
  r[4] = (bf16)b[0]; r[5] = (bf16)b[1]; r[6] = (bf16)b[2]; r[7] = (bf16)b[3];
  return r;
}

__device__ __forceinline__ bf16x8 load_cvt_frag(const float* p) {
  f32x4 a = *(const f32x4*)p;
  f32x4 b = *(const f32x4*)(p + 16);
  return cvt8(a, b);
}

// ---------------- mask bit-pack: (S,S) int32 -> S*S/64 uint64 ----------------
__global__ __launch_bounds__(256) void pack_mask_k(const int* __restrict__ mask,
                                                   u64* __restrict__ bits) {
  const int w = blockIdx.x * 4 + (threadIdx.x >> 6);
  const int lane = threadIdx.x & 63;
  const int v = mask[(size_t)w * 64 + lane];
  const u64 b = __ballot(v != 0);
  if (lane == 0) bits[w] = b;
}

// ---------------- K/V projection ----------------
// Outputs are stored in MFMA-FRAGMENT-TILED order so attn_k's loads are
// fully coalesced 16B/lane:
//   KpF frag index ((bh*32 + kb)*4 + ks)*2 + c ; within frag: lane*8 + e
//     lane=(g',c16'): holds K[key=kb*64+16ks+c16'][d=32c+4g'+(e&3)+16*(e>>2)]
//   VpF frag index ((bh*32 + kb)*4 + t )*2 + c ; within frag: lane*8 + e
//     lane=(g',c16''): holds V[d=16t+c16''][key=kb*64+32c+4g'+(e&3)+16*(e>>2)]
__global__ __launch_bounds__(256) void kvproj_k(
    const float* __restrict__ Kin, const float* __restrict__ Vin,
    const float* __restrict__ Wk, const float* __restrict__ bk,
    const float* __restrict__ Wv, const float* __restrict__ bv,
    bf16* __restrict__ KpF, bf16* __restrict__ VpF) {
  // XCD swizzle: same mapping as attn_k so producer and consumer share an L2
  const int xcd = blockIdx.x & 7;
  const int idx = blockIdx.x >> 3;           // 0..127
  const int bh = xcd * 4 + (idx >> 5);       // 4 heads per XCD
  const int sblk = idx & 31;                 // S/64 = 32
  const int h = bh & (NH - 1);
  const int b = bh >> 4;
  const int lane = threadIdx.x & 63;
  const int wave = threadIdx.x >> 6;
  const int g = lane >> 4;
  const int c16 = lane & 15;
  const int sbase = sblk * 64 + wave * 16;
  const int srow = sbase + c16;

  const float* xk = Kin + ((size_t)b * S_LEN + srow) * E_DIM + h * HD;
  const float* xv = Vin + ((size_t)b * S_LEN + srow) * E_DIM + h * HD;
  bf16x8 xkf[2], xvf[2];
#pragma unroll
  for (int c = 0; c < 2; ++c) {
    xkf[c] = load_cvt_frag(xk + 32 * c + 4 * g);
    xvf[c] = load_cvt_frag(xv + 32 * c + 4 * g);
  }

  // Kp = Xk * Wk^T + bk  (A = Xk rows=keys, B = Wk^T)
#pragma unroll
  for (int nt = 0; nt < 4; ++nt) {
    const float* wr = Wk + (16 * nt + c16) * HD + 4 * g;
    f32x4 acc = {0.f, 0.f, 0.f, 0.f};
    acc = MFMA(xkf[0], load_cvt_frag(wr), acc);
    acc = MFMA(xkf[1], load_cvt_frag(wr + 32), acc);
    const float bias = bk[16 * nt + c16];
    // element (key = sbase+4g+r, d = 16nt+c16) -> fragment coords
    const size_t fidx = (((size_t)bh * 32 + sblk) * 4 + wave) * 2 + (nt >> 1);
    const int e = (c16 & 3) + 4 * (nt & 1);
#pragma unroll
    for (int r = 0; r < 4; ++r) {
      const int lane_p = (c16 >> 2) * 16 + 4 * g + r;
      KpF[fidx * 512 + lane_p * 8 + e] = (bf16)(acc[r] + bias);
    }
  }
  // Vp = Xv * Wv^T + bv, stored transposed (A = Wv rows=d_out, B = Xv^T)
#pragma unroll
  for (int nt = 0; nt < 4; ++nt) {
    const float* wr = Wv + (16 * nt + c16) * HD + 4 * g;
    f32x4 acc = {0.f, 0.f, 0.f, 0.f};
    acc = MFMA(load_cvt_frag(wr), xvf[0], acc);
    acc = MFMA(load_cvt_frag(wr + 32), xvf[1], acc);
    // element (dout = 16nt+4g+r, key = sblk*64 + wave*16 + c16)
    const size_t fidx = (((size_t)bh * 32 + sblk) * 4 + nt) * 2 + (wave >> 1);
    const int e = (c16 & 3) + 4 * (wave & 1);
#pragma unroll
    for (int r = 0; r < 4; ++r) {
      const int dout = 16 * nt + 4 * g + r;
      const int lane_p = (c16 >> 2) * 16 + 4 * g + r;
      VpF[fidx * 512 + lane_p * 8 + e] = (bf16)(acc[r] + bv[dout]);
    }
  }
}

// ---------------- attention: fused Q-proj + swapped-operand flash ----------------
__global__ __launch_bounds__(256) void attn_k(
    const float* __restrict__ Qin, const float* __restrict__ Wq, const float* __restrict__ bq,
    const bf16* __restrict__ KpF, const bf16* __restrict__ VpF,
    const u64* __restrict__ mbits, float* __restrict__ out) {
  const int xcd = blockIdx.x & 7;
  const int idx = blockIdx.x >> 3;
  const int bh = xcd * 4 + (idx >> 5);
  const int qblk = idx & 31;
  const int h = bh & (NH - 1);
  const int b = bh >> 4;
  const int lane = threadIdx.x & 63;
  const int wave = threadIdx.x >> 6;
  const int g = lane >> 4;
  const int c16 = lane & 15;
  const int qbase = qblk * 64 + wave * 16;
  const int qrow = qbase + c16;   // each lane owns ONE q row (swapped layout)

  // Q projection in-register: QpT = Wq * Xq^T + bq; C-tiles ARE the QK B-frags.
  const float* xq = Qin + ((size_t)b * S_LEN + qrow) * E_DIM + h * HD;
  bf16x8 xqf[2];
#pragma unroll
  for (int c = 0; c < 2; ++c) xqf[c] = load_cvt_frag(xq + 32 * c + 4 * g);
  f32x4 qt[4];
#pragma unroll
  for (int t = 0; t < 4; ++t) {
    const float* wr = Wq + (16 * t + c16) * HD + 4 * g;
    f32x4 acc = {0.f, 0.f, 0.f, 0.f};
    acc = MFMA(load_cvt_frag(wr), xqf[0], acc);
    acc = MFMA(load_cvt_frag(wr + 32), xqf[1], acc);
#pragma unroll
    for (int r = 0; r < 4; ++r) acc[r] += bq[16 * t + 4 * g + r];
    qt[t] = acc;
  }
  bf16x8 qfrag[2];
#pragma unroll
  for (int c = 0; c < 2; ++c) qfrag[c] = cvt8(qt[2 * c], qt[2 * c + 1]);

  // fragment-tiled bases: per bh, 32 kb-blocks x 8 frags x 64 lanes (bf16x8 each)
  const bf16x8* kf_base = (const bf16x8*)KpF + (size_t)bh * 32 * 8 * 64 + lane;
  const bf16x8* vf_base = (const bf16x8*)VpF + (size_t)bh * 32 * 8 * 64 + lane;
  const u64* mrow = mbits + (size_t)qrow * (S_LEN / 64);

  float m = -1e30f, l = 0.f;
  f32x4 o[4] = {};

  for (int kb = 0; kb < S_LEN / 64; ++kb) {
    const u64 mw = mrow[kb];
    // K fragments: one coalesced 16B/lane load each
    const bf16x8* kf = kf_base + (size_t)kb * 512;
    bf16x8 kfr[8];
#pragma unroll
    for (int f = 0; f < 8; ++f) kfr[f] = kf[f * 64];
    // S^T tiles: st[ks][r] = score(key = kb*64 + 16*ks + 4*g + r, q = qrow)
    f32x4 st[4];
#pragma unroll
    for (int ks = 0; ks < 4; ++ks) {
      f32x4 acc = {0.f, 0.f, 0.f, 0.f};
      acc = MFMA(kfr[2 * ks], qfrag[0], acc);
      acc = MFMA(kfr[2 * ks + 1], qfrag[1], acc);
      st[ks] = acc;
    }
    // V fragments issued now; latency hides under the softmax VALU work
    const bf16x8* vf = vf_base + (size_t)kb * 512;
    bf16x8 vfr[8];
#pragma unroll
    for (int f = 0; f < 8; ++f) vfr[f] = vf[f * 64];

    float tm = -1e30f;
#pragma unroll
    for (int ks = 0; ks < 4; ++ks)
#pragma unroll
      for (int r = 0; r < 4; ++r) {
        const float x =
            ((mw >> (16 * ks + 4 * g + r)) & 1ull) ? st[ks][r] * SCALE_L2E : -1e30f;
        st[ks][r] = x;
        tm = fmaxf(tm, x);
      }
    tm = fmaxf(tm, __shfl_xor(tm, 16));
    tm = fmaxf(tm, __shfl_xor(tm, 32));
    const float mnew = fmaxf(m, tm);
    const float corr = exp2f(m - mnew);
    float psum = 0.f;
#pragma unroll
    for (int ks = 0; ks < 4; ++ks)
#pragma unroll
      for (int r = 0; r < 4; ++r) {
        const float p = exp2f(st[ks][r] - mnew);
        st[ks][r] = p;
        psum += p;
      }
    psum += __shfl_xor(psum, 16);
    psum += __shfl_xor(psum, 32);
    l = l * corr + psum;
    m = mnew;
#pragma unroll
    for (int t = 0; t < 4; ++t)
#pragma unroll
      for (int r = 0; r < 4; ++r) o[t][r] *= corr;
    // P^T C-tiles are directly the PV B-frags
    bf16x8 pfrag[2];
#pragma unroll
    for (int c = 0; c < 2; ++c) pfrag[c] = cvt8(st[2 * c], st[2 * c + 1]);
#pragma unroll
    for (int t = 0; t < 4; ++t) {
      o[t] = MFMA(vfr[2 * t], pfrag[0], o[t]);
      o[t] = MFMA(vfr[2 * t + 1], pfrag[1], o[t]);
    }
  }

  const float inv = 1.0f / l;
  float* orow = out + ((size_t)b * S_LEN + qrow) * E_DIM + h * HD;
#pragma unroll
  for (int t = 0; t < 4; ++t) {
    f32x4 v;
#pragma unroll
    for (int r = 0; r < 4; ++r) v[r] = o[t][r] * inv;
    *(f32x4*)(orow + 16 * t + 4 * g) = v;
  }
}

extern "C" void kernel_launch(void* const* d_in, const int* in_sizes, int n_in,
                              void* d_out, int out_size, void* d_ws, size_t ws_size,
                              hipStream_t stream) {
  const float* Q = (const float*)d_in[0];
  const float* K = (const float*)d_in[1];
  const float* V = (const float*)d_in[2];
  const int* mask = (const int*)d_in[3];
  const float* Wq = (const float*)d_in[4];
  const float* bq = (const float*)d_in[5];
  const float* Wk = (const float*)d_in[6];
  const float* bk = (const float*)d_in[7];
  const float* Wv = (const float*)d_in[8];
  const float* bv = (const float*)d_in[9];
  float* out = (float*)d_out;
  const int B = in_sizes[0] / (S_LEN * E_DIM);   // = 2

  char* ws = (char*)d_ws;
  const size_t proj_bytes = (size_t)B * NH * S_LEN * HD * 2;  // 8 MB each
  bf16* KpF = (bf16*)ws;
  bf16* VpF = (bf16*)(ws + proj_bytes);
  u64* mbits = (u64*)(ws + 2 * proj_bytes);      // 512 KB

  pack_mask_k<<<(S_LEN * S_LEN / 64) / 4, 256, 0, stream>>>(mask, mbits);
  kvproj_k<<<B * NH * (S_LEN / 64), 256, 0, stream>>>(K, V, Wk, bk, Wv, bv, KpF, VpF);
  attn_k<<<B * NH * (S_LEN / 64), 256, 0, stream>>>(Q, Wq, bq, KpF, VpF, mbits, out);
}

// Round 3
// 141.365 us; speedup vs baseline: 3.5704x; 1.4668x over previous
//
#include <hip/hip_runtime.h>

#define S_LEN 2048
#define E_DIM 1024
#define NH 16
#define HD 64
#define NT (S_LEN / 64)
// (1/sqrt(64)) * log2(e): fold softmax scale into log2 domain (applied to Q pre-cvt)
#define SCALE_L2E 0.18033688011112042f

typedef __bf16 bf16;
typedef __attribute__((ext_vector_type(4))) bf16 bf16x4;
typedef __attribute__((ext_vector_type(8))) bf16 bf16x8;
typedef __attribute__((ext_vector_type(4))) float f32x4;
typedef unsigned long long u64;
typedef unsigned int u32;

#define MFMA(a, b, c) __builtin_amdgcn_mfma_f32_16x16x32_bf16((a), (b), (c), 0, 0, 0)

__device__ __forceinline__ bf16x8 cvt8(f32x4 a, f32x4 b) {
  bf16x8 r;
  r[0] = (bf16)a[0]; r[1] = (bf16)a[1]; r[2] = (bf16)a[2]; r[3] = (bf16)a[3];
  r[4] = (bf16)b[0]; r[5] = (bf16)b[1]; r[6] = (bf16)b[2]; r[7] = (bf16)b[3];
  return r;
}

__device__ __forceinline__ bf16x8 load_cvt_frag(const float* p) {
  f32x4 a = *(const f32x4*)p;
  f32x4 b = *(const f32x4*)(p + 16);
  return cvt8(a, b);
}

// ---------------- mask bit-pack: (S,S) int32 -> S*S/64 uint64 ----------------
__global__ __launch_bounds__(256) void pack_mask_k(const int* __restrict__ mask,
                                                   u64* __restrict__ bits) {
  const int w = blockIdx.x * 4 + (threadIdx.x >> 6);
  const int lane = threadIdx.x & 63;
  const int v = mask[(size_t)w * 64 + lane];
  const u64 b = __ballot(v != 0);
  if (lane == 0) bits[w] = b;
}

// ---------------- K/V projection (unchanged from R2) ----------------
// Outputs stored in MFMA-FRAGMENT-TILED order; per (bh,kb) the 8 K frags
// (then 8 V frags) are 512 bf16 each, contiguous -> attn stages them with
// linear global_load_lds.
__global__ __launch_bounds__(256) void kvproj_k(
    const float* __restrict__ Kin, const float* __restrict__ Vin,
    const float* __restrict__ Wk, const float* __restrict__ bk,
    const float* __restrict__ Wv, const float* __restrict__ bv,
    bf16* __restrict__ KpF, bf16* __restrict__ VpF) {
  const int xcd = blockIdx.x & 7;
  const int idx = blockIdx.x >> 3;           // 0..127
  const int bh = xcd * 4 + (idx >> 5);       // 4 heads per XCD
  const int sblk = idx & 31;                 // S/64 = 32
  const int h = bh & (NH - 1);
  const int b = bh >> 4;
  const int lane = threadIdx.x & 63;
  const int wave = threadIdx.x >> 6;
  const int g = lane >> 4;
  const int c16 = lane & 15;
  const int sbase = sblk * 64 + wave * 16;
  const int srow = sbase + c16;

  const float* xk = Kin + ((size_t)b * S_LEN + srow) * E_DIM + h * HD;
  const float* xv = Vin + ((size_t)b * S_LEN + srow) * E_DIM + h * HD;
  bf16x8 xkf[2], xvf[2];
#pragma unroll
  for (int c = 0; c < 2; ++c) {
    xkf[c] = load_cvt_frag(xk + 32 * c + 4 * g);
    xvf[c] = load_cvt_frag(xv + 32 * c + 4 * g);
  }

  // Kp = Xk * Wk^T + bk
#pragma unroll
  for (int nt = 0; nt < 4; ++nt) {
    const float* wr = Wk + (16 * nt + c16) * HD + 4 * g;
    f32x4 acc = {0.f, 0.f, 0.f, 0.f};
    acc = MFMA(xkf[0], load_cvt_frag(wr), acc);
    acc = MFMA(xkf[1], load_cvt_frag(wr + 32), acc);
    const float bias = bk[16 * nt + c16];
    const size_t fidx = (((size_t)bh * 32 + sblk) * 4 + wave) * 2 + (nt >> 1);
    const int e = (c16 & 3) + 4 * (nt & 1);
#pragma unroll
    for (int r = 0; r < 4; ++r) {
      const int lane_p = (c16 >> 2) * 16 + 4 * g + r;
      KpF[fidx * 512 + lane_p * 8 + e] = (bf16)(acc[r] + bias);
    }
  }
  // Vp (transposed): A = Wv rows=d_out, B = Xv^T
#pragma unroll
  for (int nt = 0; nt < 4; ++nt) {
    const float* wr = Wv + (16 * nt + c16) * HD + 4 * g;
    f32x4 acc = {0.f, 0.f, 0.f, 0.f};
    acc = MFMA(load_cvt_frag(wr), xvf[0], acc);
    acc = MFMA(load_cvt_frag(wr + 32), xvf[1], acc);
    const size_t fidx = (((size_t)bh * 32 + sblk) * 4 + nt) * 2 + (wave >> 1);
    const int e = (c16 & 3) + 4 * (wave & 1);
#pragma unroll
    for (int r = 0; r < 4; ++r) {
      const int dout = 16 * nt + 4 * g + r;
      const int lane_p = (c16 >> 2) * 16 + 4 * g + r;
      VpF[fidx * 512 + lane_p * 8 + e] = (bf16)(acc[r] + bv[dout]);
    }
  }
}

// ---------------- attention: fused Q-proj + LDS-staged swapped flash ----------------
__global__ __launch_bounds__(256) void attn_k(
    const float* __restrict__ Qin, const float* __restrict__ Wq, const float* __restrict__ bq,
    const bf16* __restrict__ KpF, const bf16* __restrict__ VpF,
    const u64* __restrict__ mbits, float* __restrict__ out) {
  const int xcd = blockIdx.x & 7;
  const int idx = blockIdx.x >> 3;
  const int bh = xcd * 4 + (idx >> 5);
  const int qblk = idx & 31;
  const int h = bh & (NH - 1);
  const int b = bh >> 4;
  const int lane = threadIdx.x & 63;
  const int wave = threadIdx.x >> 6;
  const int g = lane >> 4;
  const int c16 = lane & 15;
  const int qrow = qblk * 64 + wave * 16 + c16;  // each lane owns ONE q row

  // double-buffered K/V fragment tiles: 2 bufs x (8K + 8V) frags x 1KB = 32 KB
  __shared__ __align__(16) bf16 lds_k[2][8 * 512];
  __shared__ __align__(16) bf16 lds_v[2][8 * 512];

  const bf16* ktile = KpF + ((size_t)bh * 32) * 4096;  // + kb*4096
  const bf16* vtile = VpF + ((size_t)bh * 32) * 4096;

  // Q projection in-register; fold softmax scale into Q before bf16 cvt.
  const float* xq = Qin + ((size_t)b * S_LEN + qrow) * E_DIM + h * HD;
  bf16x8 xqf[2];
#pragma unroll
  for (int c = 0; c < 2; ++c) xqf[c] = load_cvt_frag(xq + 32 * c + 4 * g);
  f32x4 qt[4];
#pragma unroll
  for (int t = 0; t < 4; ++t) {
    const float* wr = Wq + (16 * t + c16) * HD + 4 * g;
    f32x4 acc = {0.f, 0.f, 0.f, 0.f};
    acc = MFMA(load_cvt_frag(wr), xqf[0], acc);
    acc = MFMA(load_cvt_frag(wr + 32), xqf[1], acc);
#pragma unroll
    for (int r = 0; r < 4; ++r) acc[r] = (acc[r] + bq[16 * t + 4 * g + r]) * SCALE_L2E;
    qt[t] = acc;
  }
  bf16x8 qfrag[2];
#pragma unroll
  for (int c = 0; c < 2; ++c) qfrag[c] = cvt8(qt[2 * c], qt[2 * c + 1]);

  const u64* mrow = mbits + (size_t)qrow * NT;

  float m = -1e30f, l = 0.f;
  f32x4 o[4] = {};

  // stage kb=0 into buf 0: wave w moves K frags {2w,2w+1} and V frags {2w,2w+1}
#pragma unroll
  for (int i = 0; i < 2; ++i) {
    const int f = 2 * wave + i;
    __builtin_amdgcn_global_load_lds(
        (const __attribute__((address_space(1))) u32*)(ktile + f * 512 + lane * 8),
        (__attribute__((address_space(3))) u32*)&lds_k[0][f * 512], 16, 0, 0);
    __builtin_amdgcn_global_load_lds(
        (const __attribute__((address_space(1))) u32*)(vtile + f * 512 + lane * 8),
        (__attribute__((address_space(3))) u32*)&lds_v[0][f * 512], 16, 0, 0);
  }
  __syncthreads();

  int cur = 0;
  for (int kb = 0; kb < NT; ++kb) {
    // issue next tile's staging first: latency hides under this iteration
    if (kb + 1 < NT) {
      const bf16* kn = ktile + (size_t)(kb + 1) * 4096;
      const bf16* vn = vtile + (size_t)(kb + 1) * 4096;
#pragma unroll
      for (int i = 0; i < 2; ++i) {
        const int f = 2 * wave + i;
        __builtin_amdgcn_global_load_lds(
            (const __attribute__((address_space(1))) u32*)(kn + f * 512 + lane * 8),
            (__attribute__((address_space(3))) u32*)&lds_k[cur ^ 1][f * 512], 16, 0, 0);
        __builtin_amdgcn_global_load_lds(
            (const __attribute__((address_space(1))) u32*)(vn + f * 512 + lane * 8),
            (__attribute__((address_space(3))) u32*)&lds_v[cur ^ 1][f * 512], 16, 0, 0);
      }
    }
    const u64 mw = mrow[kb];

    // QK^T: interleave ds_read pairs with MFMA; st[ks][r] = score(key=kb*64+16ks+4g+r, qrow)
    f32x4 st[4];
    __builtin_amdgcn_s_setprio(1);
#pragma unroll
    for (int ks = 0; ks < 4; ++ks) {
      const bf16x8 k0 = *(const bf16x8*)&lds_k[cur][(2 * ks) * 512 + lane * 8];
      const bf16x8 k1 = *(const bf16x8*)&lds_k[cur][(2 * ks + 1) * 512 + lane * 8];
      f32x4 acc = {0.f, 0.f, 0.f, 0.f};
      acc = MFMA(k0, qfrag[0], acc);
      acc = MFMA(k1, qfrag[1], acc);
      st[ks] = acc;
    }
    __builtin_amdgcn_s_setprio(0);

    // V fragment reads issue now; latency hides under softmax
    bf16x8 vfr[8];
#pragma unroll
    for (int f = 0; f < 8; ++f) vfr[f] = *(const bf16x8*)&lds_v[cur][f * 512 + lane * 8];

    float tm = -1e30f;
#pragma unroll
    for (int ks = 0; ks < 4; ++ks)
#pragma unroll
      for (int r = 0; r < 4; ++r) {
        const float x = ((mw >> (16 * ks + 4 * g + r)) & 1ull) ? st[ks][r] : -1e30f;
        st[ks][r] = x;
        tm = fmaxf(tm, x);
      }
    tm = fmaxf(tm, __shfl_xor(tm, 16));
    tm = fmaxf(tm, __shfl_xor(tm, 32));

    // exact defer-rescale: skip o/l rescale when the running max didn't grow
    if (!__all(tm <= m)) {
      const float mnew = fmaxf(m, tm);
      const float corr = exp2f(m - mnew);
#pragma unroll
      for (int t = 0; t < 4; ++t)
#pragma unroll
        for (int r = 0; r < 4; ++r) o[t][r] *= corr;
      l *= corr;
      m = mnew;
    }
    float psum = 0.f;
#pragma unroll
    for (int ks = 0; ks < 4; ++ks)
#pragma unroll
      for (int r = 0; r < 4; ++r) {
        const float p = exp2f(st[ks][r] - m);
        st[ks][r] = p;
        psum += p;
      }
    psum += __shfl_xor(psum, 16);
    psum += __shfl_xor(psum, 32);
    l += psum;

    bf16x8 pfrag[2];
#pragma unroll
    for (int c = 0; c < 2; ++c) pfrag[c] = cvt8(st[2 * c], st[2 * c + 1]);
    __builtin_amdgcn_s_setprio(1);
#pragma unroll
    for (int t = 0; t < 4; ++t) {
      o[t] = MFMA(vfr[2 * t], pfrag[0], o[t]);
      o[t] = MFMA(vfr[2 * t + 1], pfrag[1], o[t]);
    }
    __builtin_amdgcn_s_setprio(0);

    // barrier implies vmcnt(0)+lgkmcnt(0): staging into cur^1 complete, all
    // waves done reading cur -> safe to overwrite next iteration
    __syncthreads();
    cur ^= 1;
  }

  const float inv = 1.0f / l;
  float* orow = out + ((size_t)b * S_LEN + qrow) * E_DIM + h * HD;
#pragma unroll
  for (int t = 0; t < 4; ++t) {
    f32x4 v;
#pragma unroll
    for (int r = 0; r < 4; ++r) v[r] = o[t][r] * inv;
    *(f32x4*)(orow + 16 * t + 4 * g) = v;
  }
}

extern "C" void kernel_launch(void* const* d_in, const int* in_sizes, int n_in,
                              void* d_out, int out_size, void* d_ws, size_t ws_size,
                              hipStream_t stream) {
  const float* Q = (const float*)d_in[0];
  const float* K = (const float*)d_in[1];
  const float* V = (const float*)d_in[2];
  const int* mask = (const int*)d_in[3];
  const float* Wq = (const float*)d_in[4];
  const float* bq = (const float*)d_in[5];
  const float* Wk = (const float*)d_in[6];
  const float* bk = (const float*)d_in[7];
  const float* Wv = (const float*)d_in[8];
  const float* bv = (const float*)d_in[9];
  float* out = (float*)d_out;
  const int B = in_sizes[0] / (S_LEN * E_DIM);   // = 2

  char* ws = (char*)d_ws;
  const size_t proj_bytes = (size_t)B * NH * S_LEN * HD * 2;  // 8 MB each
  bf16* KpF = (bf16*)ws;
  bf16* VpF = (bf16*)(ws + proj_bytes);
  u64* mbits = (u64*)(ws + 2 * proj_bytes);      // 512 KB

  pack_mask_k<<<(S_LEN * S_LEN / 64) / 4, 256, 0, stream>>>(mask, mbits);
  kvproj_k<<<B * NH * (S_LEN / 64), 256, 0, stream>>>(K, V, Wk, bk, Wv, bv, KpF, VpF);
  attn_k<<<B * NH * (S_LEN / 64), 256, 0, stream>>>(Q, Wq, bq, KpF, VpF, mbits, out);
}

// Round 4
// 135.175 us; speedup vs baseline: 3.7340x; 1.0458x over previous
//
#include <hip/hip_runtime.h>

#define S_LEN 2048
#define E_DIM 1024
#define NH 16
#define HD 64
#define NT (S_LEN / 64)
// (1/sqrt(64)) * log2(e): fold softmax scale into log2 domain (applied to Q pre-cvt)
#define SCALE_L2E 0.18033688011112042f
#define DEFER_THR 8.0f

typedef __bf16 bf16;
typedef __attribute__((ext_vector_type(4))) bf16 bf16x4;
typedef __attribute__((ext_vector_type(8))) bf16 bf16x8;
typedef __attribute__((ext_vector_type(4))) float f32x4;
typedef unsigned long long u64;
typedef unsigned int u32;

#define MFMA(a, b, c) __builtin_amdgcn_mfma_f32_16x16x32_bf16((a), (b), (c), 0, 0, 0)

__device__ __forceinline__ bf16x8 cvt8(f32x4 a, f32x4 b) {
  bf16x8 r;
  r[0] = (bf16)a[0]; r[1] = (bf16)a[1]; r[2] = (bf16)a[2]; r[3] = (bf16)a[3];
  r[4] = (bf16)b[0]; r[5] = (bf16)b[1]; r[6] = (bf16)b[2]; r[7] = (bf16)b[3];
  return r;
}

__device__ __forceinline__ bf16x8 load_cvt_frag(const float* p) {
  f32x4 a = *(const f32x4*)(p);
  f32x4 b = *(const f32x4*)(p + 16);
  return cvt8(a, b);
}

// ---------------- mask bit-pack: (S,S) int32 -> S*S/64 uint64 ----------------
__global__ __launch_bounds__(256) void pack_mask_k(const int* __restrict__ mask,
                                                   u64* __restrict__ bits) {
  const int w = blockIdx.x * 4 + (threadIdx.x >> 6);
  const int lane = threadIdx.x & 63;
  const int v = mask[(size_t)w * 64 + lane];
  const u64 b = __ballot(v != 0);
  if (lane == 0) bits[w] = b;
}

// ---------------- K/V projection (unchanged from R3) ----------------
__global__ __launch_bounds__(256) void kvproj_k(
    const float* __restrict__ Kin, const float* __restrict__ Vin,
    const float* __restrict__ Wk, const float* __restrict__ bk,
    const float* __restrict__ Wv, const float* __restrict__ bv,
    bf16* __restrict__ KpF, bf16* __restrict__ VpF) {
  const int xcd = blockIdx.x & 7;
  const int idx = blockIdx.x >> 3;           // 0..127
  const int bh = xcd * 4 + (idx >> 5);       // 4 heads per XCD
  const int sblk = idx & 31;                 // S/64 = 32
  const int h = bh & (NH - 1);
  const int b = bh >> 4;
  const int lane = threadIdx.x & 63;
  const int wave = threadIdx.x >> 6;
  const int g = lane >> 4;
  const int c16 = lane & 15;
  const int sbase = sblk * 64 + wave * 16;
  const int srow = sbase + c16;

  const float* xk = Kin + ((size_t)b * S_LEN + srow) * E_DIM + h * HD;
  const float* xv = Vin + ((size_t)b * S_LEN + srow) * E_DIM + h * HD;
  bf16x8 xkf[2], xvf[2];
#pragma unroll
  for (int c = 0; c < 2; ++c) {
    xkf[c] = load_cvt_frag(xk + 32 * c + 4 * g);
    xvf[c] = load_cvt_frag(xv + 32 * c + 4 * g);
  }

  // Kp = Xk * Wk^T + bk
#pragma unroll
  for (int nt = 0; nt < 4; ++nt) {
    const float* wr = Wk + (16 * nt + c16) * HD + 4 * g;
    f32x4 acc = {0.f, 0.f, 0.f, 0.f};
    acc = MFMA(xkf[0], load_cvt_frag(wr), acc);
    acc = MFMA(xkf[1], load_cvt_frag(wr + 32), acc);
    const float bias = bk[16 * nt + c16];
    const size_t fidx = (((size_t)bh * 32 + sblk) * 4 + wave) * 2 + (nt >> 1);
    const int e = (c16 & 3) + 4 * (nt & 1);
#pragma unroll
    for (int r = 0; r < 4; ++r) {
      const int lane_p = (c16 >> 2) * 16 + 4 * g + r;
      KpF[fidx * 512 + lane_p * 8 + e] = (bf16)(acc[r] + bias);
    }
  }
  // Vp (transposed): A = Wv rows=d_out, B = Xv^T
#pragma unroll
  for (int nt = 0; nt < 4; ++nt) {
    const float* wr = Wv + (16 * nt + c16) * HD + 4 * g;
    f32x4 acc = {0.f, 0.f, 0.f, 0.f};
    acc = MFMA(load_cvt_frag(wr), xvf[0], acc);
    acc = MFMA(load_cvt_frag(wr + 32), xvf[1], acc);
    const size_t fidx = (((size_t)bh * 32 + sblk) * 4 + nt) * 2 + (wave >> 1);
    const int e = (c16 & 3) + 4 * (wave & 1);
#pragma unroll
    for (int r = 0; r < 4; ++r) {
      const int dout = 16 * nt + 4 * g + r;
      const int lane_p = (c16 >> 2) * 16 + 4 * g + r;
      VpF[fidx * 512 + lane_p * 8 + e] = (bf16)(acc[r] + bv[dout]);
    }
  }
}

// ---------------- attention: fused Q-proj + LDS-staged swapped flash ----------------
__global__ __launch_bounds__(256) void attn_k(
    const float* __restrict__ Qin, const float* __restrict__ Wq, const float* __restrict__ bq,
    const bf16* __restrict__ KpF, const bf16* __restrict__ VpF,
    const u64* __restrict__ mbits, float* __restrict__ out) {
  const int xcd = blockIdx.x & 7;
  const int idx = blockIdx.x >> 3;
  const int bh = xcd * 4 + (idx >> 5);
  const int qblk = idx & 31;
  const int h = bh & (NH - 1);
  const int b = bh >> 4;
  const int lane = threadIdx.x & 63;
  const int wave = threadIdx.x >> 6;
  const int g = lane >> 4;
  const int c16 = lane & 15;
  const int qrow = qblk * 64 + wave * 16 + c16;  // each lane owns ONE q row

  // double-buffered K/V fragment tiles: 2 bufs x (8K + 8V) frags x 1KB = 32 KB
  __shared__ __align__(16) bf16 lds_k[2][8 * 512];
  __shared__ __align__(16) bf16 lds_v[2][8 * 512];

  const bf16* ktile = KpF + ((size_t)bh * 32) * 4096;  // + kb*4096
  const bf16* vtile = VpF + ((size_t)bh * 32) * 4096;

  // Q projection in-register; fold softmax scale into Q before bf16 cvt.
  const float* xq = Qin + ((size_t)b * S_LEN + qrow) * E_DIM + h * HD;
  bf16x8 xqf[2];
#pragma unroll
  for (int c = 0; c < 2; ++c) xqf[c] = load_cvt_frag(xq + 32 * c + 4 * g);
  f32x4 qt[4];
#pragma unroll
  for (int t = 0; t < 4; ++t) {
    const float* wr = Wq + (16 * t + c16) * HD + 4 * g;
    f32x4 acc = {0.f, 0.f, 0.f, 0.f};
    acc = MFMA(load_cvt_frag(wr), xqf[0], acc);
    acc = MFMA(load_cvt_frag(wr + 32), xqf[1], acc);
#pragma unroll
    for (int r = 0; r < 4; ++r) acc[r] = (acc[r] + bq[16 * t + 4 * g + r]) * SCALE_L2E;
    qt[t] = acc;
  }
  bf16x8 qfrag[2];
#pragma unroll
  for (int c = 0; c < 2; ++c) qfrag[c] = cvt8(qt[2 * c], qt[2 * c + 1]);

  // constant all-ones A-fragment: o5 = MFMA(ones, pfrag) accumulates sum(P) per q col
  bf16x8 ones;
#pragma unroll
  for (int i = 0; i < 8; ++i) ones[i] = (bf16)1.0f;

  const u64* mrow = mbits + (size_t)qrow * NT;

  float m = -1e30f;
  f32x4 o[4] = {};
  f32x4 o5 = {};

  // stage kb=0 into buf 0: wave w moves K frags {2w,2w+1} and V frags {2w,2w+1}
#pragma unroll
  for (int i = 0; i < 2; ++i) {
    const int f = 2 * wave + i;
    __builtin_amdgcn_global_load_lds(
        (const __attribute__((address_space(1))) u32*)(ktile + f * 512 + lane * 8),
        (__attribute__((address_space(3))) u32*)&lds_k[0][f * 512], 16, 0, 0);
    __builtin_amdgcn_global_load_lds(
        (const __attribute__((address_space(1))) u32*)(vtile + f * 512 + lane * 8),
        (__attribute__((address_space(3))) u32*)&lds_v[0][f * 512], 16, 0, 0);
  }
  __syncthreads();

  int cur = 0;
  for (int kb = 0; kb < NT; ++kb) {
    // issue next tile's staging first: latency hides under this iteration
    if (kb + 1 < NT) {
      const bf16* kn = ktile + (size_t)(kb + 1) * 4096;
      const bf16* vn = vtile + (size_t)(kb + 1) * 4096;
#pragma unroll
      for (int i = 0; i < 2; ++i) {
        const int f = 2 * wave + i;
        __builtin_amdgcn_global_load_lds(
            (const __attribute__((address_space(1))) u32*)(kn + f * 512 + lane * 8),
            (__attribute__((address_space(3))) u32*)&lds_k[cur ^ 1][f * 512], 16, 0, 0);
        __builtin_amdgcn_global_load_lds(
            (const __attribute__((address_space(1))) u32*)(vn + f * 512 + lane * 8),
            (__attribute__((address_space(3))) u32*)&lds_v[cur ^ 1][f * 512], 16, 0, 0);
      }
    }
    const u64 mw = mrow[kb];
    const u64 mws = mw >> (4 * g);   // element bit positions now compile-time consts
    const u32 mlo = (u32)mws;
    const u32 mhi = (u32)(mws >> 32);

    // QK^T: st[ks][r] = score(key = kb*64 + 16*ks + 4*g + r, q = qrow)
    f32x4 st[4];
    __builtin_amdgcn_s_setprio(1);
#pragma unroll
    for (int ks = 0; ks < 4; ++ks) {
      const bf16x8 k0 = *(const bf16x8*)&lds_k[cur][(2 * ks) * 512 + lane * 8];
      const bf16x8 k1 = *(const bf16x8*)&lds_k[cur][(2 * ks + 1) * 512 + lane * 8];
      f32x4 acc = {0.f, 0.f, 0.f, 0.f};
      acc = MFMA(k0, qfrag[0], acc);
      acc = MFMA(k1, qfrag[1], acc);
      st[ks] = acc;
    }
    __builtin_amdgcn_s_setprio(0);

    // V fragment reads issue now; latency hides under softmax
    bf16x8 vfr[8];
#pragma unroll
    for (int f = 0; f < 8; ++f) vfr[f] = *(const bf16x8*)&lds_v[cur][f * 512 + lane * 8];

    // local max over this lane's 16 raw scores (upper bound incl masked -> safe)
    const float tm = fmaxf(
        fmaxf(fmaxf(fmaxf(st[0][0], st[0][1]), fmaxf(st[0][2], st[0][3])),
              fmaxf(fmaxf(st[1][0], st[1][1]), fmaxf(st[1][2], st[1][3]))),
        fmaxf(fmaxf(fmaxf(st[2][0], st[2][1]), fmaxf(st[2][2], st[2][3])),
              fmaxf(fmaxf(st[3][0], st[3][1]), fmaxf(st[3][2], st[3][3]))));

    // defer-max: only reduce + rescale when some lane's tile max grew past m+THR
    if (!__all(tm <= m + DEFER_THR)) {
      float tmax = fmaxf(tm, __shfl_xor(tm, 16));
      tmax = fmaxf(tmax, __shfl_xor(tmax, 32));
      const float mnew = fmaxf(m, tmax);
      const float corr = exp2f(m - mnew);
#pragma unroll
      for (int t = 0; t < 4; ++t)
#pragma unroll
        for (int r = 0; r < 4; ++r) o[t][r] *= corr;
#pragma unroll
      for (int r = 0; r < 4; ++r) o5[r] *= corr;
      m = mnew;
    }

    // p = exp2(st - m), then zero masked elems: bfe_i32(bit)->0/-1, AND on f32 bits
#pragma unroll
    for (int ks = 0; ks < 4; ++ks) {
      const u32 mword = (ks < 2) ? mlo : mhi;
      const int base = (ks & 1) * 16;
#pragma unroll
      for (int r = 0; r < 4; ++r) {
        const float p = exp2f(st[ks][r] - m);
        const int keep = __builtin_amdgcn_sbfe(mword, base + r, 1);  // 0 or -1
        st[ks][r] = __uint_as_float(__float_as_uint(p) & (u32)keep);
      }
    }

    bf16x8 pfrag[2];
#pragma unroll
    for (int c = 0; c < 2; ++c) pfrag[c] = cvt8(st[2 * c], st[2 * c + 1]);
    __builtin_amdgcn_s_setprio(1);
#pragma unroll
    for (int t = 0; t < 4; ++t) {
      o[t] = MFMA(vfr[2 * t], pfrag[0], o[t]);
      o[t] = MFMA(vfr[2 * t + 1], pfrag[1], o[t]);
    }
    // row-sum of P via ones-fragment: replaces 16 VALU adds + 2 shfl reduces
    o5 = MFMA(ones, pfrag[0], o5);
    o5 = MFMA(ones, pfrag[1], o5);
    __builtin_amdgcn_s_setprio(0);

    // barrier implies vmcnt(0)+lgkmcnt(0): staging into cur^1 complete, all
    // waves done reading cur -> safe to overwrite next iteration
    __syncthreads();
    cur ^= 1;
  }

  const float inv = 1.0f / o5[0];
  float* orow = out + ((size_t)b * S_LEN + qrow) * E_DIM + h * HD;
#pragma unroll
  for (int t = 0; t < 4; ++t) {
    f32x4 v;
#pragma unroll
    for (int r = 0; r < 4; ++r) v[r] = o[t][r] * inv;
    *(f32x4*)(orow + 16 * t + 4 * g) = v;
  }
}

extern "C" void kernel_launch(void* const* d_in, const int* in_sizes, int n_in,
                              void* d_out, int out_size, void* d_ws, size_t ws_size,
                              hipStream_t stream) {
  const float* Q = (const float*)d_in[0];
  const float* K = (const float*)d_in[1];
  const float* V = (const float*)d_in[2];
  const int* mask = (const int*)d_in[3];
  const float* Wq = (const float*)d_in[4];
  const float* bq = (const float*)d_in[5];
  const float* Wk = (const float*)d_in[6];
  const float* bk = (const float*)d_in[7];
  const float* Wv = (const float*)d_in[8];
  const float* bv = (const float*)d_in[9];
  float* out = (float*)d_out;
  const int B = in_sizes[0] / (S_LEN * E_DIM);   // = 2

  char* ws = (char*)d_ws;
  const size_t proj_bytes = (size_t)B * NH * S_LEN * HD * 2;  // 8 MB each
  bf16* KpF = (bf16*)ws;
  bf16* VpF = (bf16*)(ws + proj_bytes);
  u64* mbits = (u64*)(ws + 2 * proj_bytes);      // 512 KB

  pack_mask_k<<<(S_LEN * S_LEN / 64) / 4, 256, 0, stream>>>(mask, mbits);
  kvproj_k<<<B * NH * (S_LEN / 64), 256, 0, stream>>>(K, V, Wk, bk, Wv, bv, KpF, VpF);
  attn_k<<<B * NH * (S_LEN / 64), 256, 0, stream>>>(Q, Wq, bq, KpF, VpF, mbits, out);
}

// Round 5
// 120.660 us; speedup vs baseline: 4.1831x; 1.1203x over previous
//
#include <hip/hip_runtime.h>

#define S_LEN 2048
#define E_DIM 1024
#define NH 16
#define HD 64
#define NT (S_LEN / 64)
// (1/sqrt(64)) * log2(e): fold softmax scale into log2 domain (applied to Q pre-cvt)
#define SCALE_L2E 0.18033688011112042f
#define DEFER_THR 8.0f

typedef __bf16 bf16;
typedef __attribute__((ext_vector_type(4))) bf16 bf16x4;
typedef __attribute__((ext_vector_type(8))) bf16 bf16x8;
typedef __attribute__((ext_vector_type(4))) float f32x4;
typedef unsigned long long u64;
typedef unsigned int u32;

#define MFMA(a, b, c) __builtin_amdgcn_mfma_f32_16x16x32_bf16((a), (b), (c), 0, 0, 0)

__device__ __forceinline__ bf16x8 cvt8(f32x4 a, f32x4 b) {
  bf16x8 r;
  r[0] = (bf16)a[0]; r[1] = (bf16)a[1]; r[2] = (bf16)a[2]; r[3] = (bf16)a[3];
  r[4] = (bf16)b[0]; r[5] = (bf16)b[1]; r[6] = (bf16)b[2]; r[7] = (bf16)b[3];
  return r;
}

__device__ __forceinline__ bf16x8 load_cvt_frag(const float* p) {
  f32x4 a = *(const f32x4*)(p);
  f32x4 b = *(const f32x4*)(p + 16);
  return cvt8(a, b);
}

// ---------------- mask bit-pack: (S,S) int32 -> TRANSPOSED bit-matrix ----------------
// bits[colblk * S + row]: a wave reading 16 consecutive rows of one colblk
// touches 128 contiguous bytes (was 16 scattered 2KB-strided lines).
__global__ __launch_bounds__(256) void pack_mask_k(const int* __restrict__ mask,
                                                   u64* __restrict__ bits) {
  const int w = blockIdx.x * 4 + (threadIdx.x >> 6);  // w = row*32 + colblk
  const int lane = threadIdx.x & 63;
  const int v = mask[(size_t)w * 64 + lane];
  const u64 b = __ballot(v != 0);
  const int row = w >> 5;
  const int colblk = w & 31;
  if (lane == 0) bits[(size_t)colblk * S_LEN + row] = b;
}

// ---------------- K/V projection (fragment-tiled outputs, unchanged) ----------------
__global__ __launch_bounds__(256) void kvproj_k(
    const float* __restrict__ Kin, const float* __restrict__ Vin,
    const float* __restrict__ Wk, const float* __restrict__ bk,
    const float* __restrict__ Wv, const float* __restrict__ bv,
    bf16* __restrict__ KpF, bf16* __restrict__ VpF) {
  const int xcd = blockIdx.x & 7;
  const int idx = blockIdx.x >> 3;           // 0..127
  const int bh = xcd * 4 + (idx >> 5);       // 4 heads per XCD
  const int sblk = idx & 31;                 // S/64 = 32
  const int h = bh & (NH - 1);
  const int b = bh >> 4;
  const int lane = threadIdx.x & 63;
  const int wave = threadIdx.x >> 6;
  const int g = lane >> 4;
  const int c16 = lane & 15;
  const int sbase = sblk * 64 + wave * 16;
  const int srow = sbase + c16;

  const float* xk = Kin + ((size_t)b * S_LEN + srow) * E_DIM + h * HD;
  const float* xv = Vin + ((size_t)b * S_LEN + srow) * E_DIM + h * HD;
  bf16x8 xkf[2], xvf[2];
#pragma unroll
  for (int c = 0; c < 2; ++c) {
    xkf[c] = load_cvt_frag(xk + 32 * c + 4 * g);
    xvf[c] = load_cvt_frag(xv + 32 * c + 4 * g);
  }

  // Kp = Xk * Wk^T + bk
#pragma unroll
  for (int nt = 0; nt < 4; ++nt) {
    const float* wr = Wk + (16 * nt + c16) * HD + 4 * g;
    f32x4 acc = {0.f, 0.f, 0.f, 0.f};
    acc = MFMA(xkf[0], load_cvt_frag(wr), acc);
    acc = MFMA(xkf[1], load_cvt_frag(wr + 32), acc);
    const float bias = bk[16 * nt + c16];
    const size_t fidx = (((size_t)bh * 32 + sblk) * 4 + wave) * 2 + (nt >> 1);
    const int e = (c16 & 3) + 4 * (nt & 1);
#pragma unroll
    for (int r = 0; r < 4; ++r) {
      const int lane_p = (c16 >> 2) * 16 + 4 * g + r;
      KpF[fidx * 512 + lane_p * 8 + e] = (bf16)(acc[r] + bias);
    }
  }
  // Vp (transposed): A = Wv rows=d_out, B = Xv^T
#pragma unroll
  for (int nt = 0; nt < 4; ++nt) {
    const float* wr = Wv + (16 * nt + c16) * HD + 4 * g;
    f32x4 acc = {0.f, 0.f, 0.f, 0.f};
    acc = MFMA(load_cvt_frag(wr), xvf[0], acc);
    acc = MFMA(load_cvt_frag(wr + 32), xvf[1], acc);
    const size_t fidx = (((size_t)bh * 32 + sblk) * 4 + nt) * 2 + (wave >> 1);
    const int e = (c16 & 3) + 4 * (wave & 1);
#pragma unroll
    for (int r = 0; r < 4; ++r) {
      const int dout = 16 * nt + 4 * g + r;
      const int lane_p = (c16 >> 2) * 16 + 4 * g + r;
      VpF[fidx * 512 + lane_p * 8 + e] = (bf16)(acc[r] + bv[dout]);
    }
  }
}

// ---------------- attention: barrier-free, register-double-buffered flash ----------------
__global__ __launch_bounds__(256, 3) void attn_k(
    const float* __restrict__ Qin, const float* __restrict__ Wq, const float* __restrict__ bq,
    const bf16* __restrict__ KpF, const bf16* __restrict__ VpF,
    const u64* __restrict__ mbits, float* __restrict__ out) {
  const int xcd = blockIdx.x & 7;
  const int idx = blockIdx.x >> 3;
  const int bh = xcd * 4 + (idx >> 5);
  const int qblk = idx & 31;
  const int h = bh & (NH - 1);
  const int b = bh >> 4;
  const int lane = threadIdx.x & 63;
  const int wave = threadIdx.x >> 6;
  const int g = lane >> 4;
  const int c16 = lane & 15;
  const int qrow = qblk * 64 + wave * 16 + c16;  // each lane owns ONE q row

  // Q projection in-register; fold softmax scale into Q before bf16 cvt.
  const float* xq = Qin + ((size_t)b * S_LEN + qrow) * E_DIM + h * HD;
  bf16x8 xqf[2];
#pragma unroll
  for (int c = 0; c < 2; ++c) xqf[c] = load_cvt_frag(xq + 32 * c + 4 * g);
  f32x4 qt[4];
#pragma unroll
  for (int t = 0; t < 4; ++t) {
    const float* wr = Wq + (16 * t + c16) * HD + 4 * g;
    f32x4 acc = {0.f, 0.f, 0.f, 0.f};
    acc = MFMA(load_cvt_frag(wr), xqf[0], acc);
    acc = MFMA(load_cvt_frag(wr + 32), xqf[1], acc);
#pragma unroll
    for (int r = 0; r < 4; ++r) acc[r] = (acc[r] + bq[16 * t + 4 * g + r]) * SCALE_L2E;
    qt[t] = acc;
  }
  bf16x8 qfrag[2];
#pragma unroll
  for (int c = 0; c < 2; ++c) qfrag[c] = cvt8(qt[2 * c], qt[2 * c + 1]);

  // constant all-ones A-fragment: o5 = MFMA(ones, pfrag) accumulates sum(P) per q col
  bf16x8 ones;
#pragma unroll
  for (int i = 0; i < 8; ++i) ones[i] = (bf16)1.0f;

  // per-lane fragment bases (16B/lane, fully coalesced)
  const bf16* ktl = KpF + ((size_t)bh * 32) * 4096 + lane * 8;  // + kb*4096 + f*512
  const bf16* vtl = VpF + ((size_t)bh * 32) * 4096 + lane * 8;
  const u64* mrowT = mbits + qrow;                              // + kb*S_LEN

  float m = -1e30f;
  f32x4 o[4] = {};
  f32x4 o5 = {};

  bf16x8 kfa[8], kfb[8], vfr[8];
  u64 mwa, mwb;

  // prologue: tile 0 K-frags + mask word
#pragma unroll
  for (int f = 0; f < 8; ++f) kfa[f] = *(const bf16x8*)(ktl + f * 512);
  mwa = mrowT[0];

  // one tile: issue next-K + cur-V + next-mask, then QK -> softmax -> PV
#define PROCESS(CURK, NXTK, MWC, MWN, KBT)                                        \
  {                                                                               \
    const int nk = ((KBT) + 1 < NT) ? (KBT) + 1 : NT - 1;                         \
    _Pragma("unroll") for (int f = 0; f < 8; ++f)                                 \
        NXTK[f] = *(const bf16x8*)(ktl + (size_t)nk * 4096 + f * 512);            \
    MWN = mrowT[(size_t)nk * S_LEN];                                              \
    _Pragma("unroll") for (int f = 0; f < 8; ++f)                                 \
        vfr[f] = *(const bf16x8*)(vtl + (size_t)(KBT) * 4096 + f * 512);          \
    f32x4 st[4];                                                                  \
    __builtin_amdgcn_s_setprio(1);                                                \
    _Pragma("unroll") for (int ks = 0; ks < 4; ++ks) {                            \
      f32x4 acc = {0.f, 0.f, 0.f, 0.f};                                           \
      acc = MFMA(CURK[2 * ks], qfrag[0], acc);                                    \
      acc = MFMA(CURK[2 * ks + 1], qfrag[1], acc);                                \
      st[ks] = acc;                                                               \
    }                                                                             \
    __builtin_amdgcn_s_setprio(0);                                                \
    const u64 mws = (MWC) >> (4 * g);                                             \
    const u32 mlo = (u32)mws;                                                     \
    const u32 mhi = (u32)(mws >> 32);                                             \
    const float tm = fmaxf(                                                       \
        fmaxf(fmaxf(fmaxf(st[0][0], st[0][1]), fmaxf(st[0][2], st[0][3])),        \
              fmaxf(fmaxf(st[1][0], st[1][1]), fmaxf(st[1][2], st[1][3]))),       \
        fmaxf(fmaxf(fmaxf(st[2][0], st[2][1]), fmaxf(st[2][2], st[2][3])),        \
              fmaxf(fmaxf(st[3][0], st[3][1]), fmaxf(st[3][2], st[3][3]))));      \
    if (!__all(tm <= m + DEFER_THR)) {                                            \
      float tmax = fmaxf(tm, __shfl_xor(tm, 16));                                 \
      tmax = fmaxf(tmax, __shfl_xor(tmax, 32));                                   \
      const float mnew = fmaxf(m, tmax);                                          \
      const float corr = exp2f(m - mnew);                                         \
      _Pragma("unroll") for (int t = 0; t < 4; ++t)                               \
          _Pragma("unroll") for (int r = 0; r < 4; ++r) o[t][r] *= corr;          \
      _Pragma("unroll") for (int r = 0; r < 4; ++r) o5[r] *= corr;                \
      m = mnew;                                                                   \
    }                                                                             \
    _Pragma("unroll") for (int ks = 0; ks < 4; ++ks) {                            \
      const u32 mword = (ks < 2) ? mlo : mhi;                                     \
      const int base = (ks & 1) * 16;                                             \
      _Pragma("unroll") for (int r = 0; r < 4; ++r) {                             \
        const float p = exp2f(st[ks][r] - m);                                     \
        const int keep = __builtin_amdgcn_sbfe(mword, base + r, 1);               \
        st[ks][r] = __uint_as_float(__float_as_uint(p) & (u32)keep);              \
      }                                                                           \
    }                                                                             \
    bf16x8 pfrag[2];                                                              \
    _Pragma("unroll") for (int c = 0; c < 2; ++c)                                 \
        pfrag[c] = cvt8(st[2 * c], st[2 * c + 1]);                                \
    __builtin_amdgcn_s_setprio(1);                                                \
    _Pragma("unroll") for (int t = 0; t < 4; ++t) {                               \
      o[t] = MFMA(vfr[2 * t], pfrag[0], o[t]);                                    \
      o[t] = MFMA(vfr[2 * t + 1], pfrag[1], o[t]);                                \
    }                                                                             \
    o5 = MFMA(ones, pfrag[0], o5);                                                \
    o5 = MFMA(ones, pfrag[1], o5);                                                \
    __builtin_amdgcn_s_setprio(0);                                                \
  }

  for (int kb2 = 0; kb2 < NT; kb2 += 2) {
    PROCESS(kfa, kfb, mwa, mwb, kb2);
    PROCESS(kfb, kfa, mwb, mwa, kb2 + 1);
  }
#undef PROCESS

  const float inv = 1.0f / o5[0];
  float* orow = out + ((size_t)b * S_LEN + qrow) * E_DIM + h * HD;
#pragma unroll
  for (int t = 0; t < 4; ++t) {
    f32x4 v;
#pragma unroll
    for (int r = 0; r < 4; ++r) v[r] = o[t][r] * inv;
    *(f32x4*)(orow + 16 * t + 4 * g) = v;
  }
}

extern "C" void kernel_launch(void* const* d_in, const int* in_sizes, int n_in,
                              void* d_out, int out_size, void* d_ws, size_t ws_size,
                              hipStream_t stream) {
  const float* Q = (const float*)d_in[0];
  const float* K = (const float*)d_in[1];
  const float* V = (const float*)d_in[2];
  const int* mask = (const int*)d_in[3];
  const float* Wq = (const float*)d_in[4];
  const float* bq = (const float*)d_in[5];
  const float* Wk = (const float*)d_in[6];
  const float* bk = (const float*)d_in[7];
  const float* Wv = (const float*)d_in[8];
  const float* bv = (const float*)d_in[9];
  float* out = (float*)d_out;
  const int B = in_sizes[0] / (S_LEN * E_DIM);   // = 2

  char* ws = (char*)d_ws;
  const size_t proj_bytes = (size_t)B * NH * S_LEN * HD * 2;  // 8 MB each
  bf16* KpF = (bf16*)ws;
  bf16* VpF = (bf16*)(ws + proj_bytes);
  u64* mbits = (u64*)(ws + 2 * proj_bytes);      // 512 KB

  pack_mask_k<<<(S_LEN * S_LEN / 64) / 4, 256, 0, stream>>>(mask, mbits);
  kvproj_k<<<B * NH * (S_LEN / 64), 256, 0, stream>>>(K, V, Wk, bk, Wv, bv, KpF, VpF);
  attn_k<<<B * NH * (S_LEN / 64), 256, 0, stream>>>(Q, Wq, bq, KpF, VpF, mbits, out);
}